// Round 7
// baseline (279.287 us; speedup 1.0000x reference)
//
#include <hip/hip_runtime.h>

// VQ-VAE VectorQuantizer: B=32, C=D=64, H=W=64, K=512
// d_in[0]: inputs  [32,64,64,64] f32 (NCHW, C = embedding dim)
// d_in[1]: embedding [512,64] f32
// d_out: [loss(1) | out(32*64*64*64) | indices(32*4096)] all read as f32
//
// V7b: V7 with the dead half-edited helper removed (compile fix; no other
// change). 3 kernels. V6's vq_full cost 129us doing ~nothing (cold scratch
// alloc at VGPR=256 + empty dispatch on critical path); vq_write was
// VMEM-issue/latency bound at 8 waves/CU (950 GB/s, 19M 4B VMEM instrs).
//   vq_prep:   e2 (numpy order) + bf16 hi/lo B-fragments + ticket zero.
//   vq_screen: single MFMA sweep, in-register top-3 (m1,i1)(m2,i2),m3;
//              packs {i1,i2,g2,g3} into out_idx (exact in fp32, <2^20).
//   vq_write:  2 threads/position (32 dims each) for 2x TLP; decodes flags:
//              g2 (~4%): lane-local exact pair-resolve with split-order
//                helpers replicating the sequential rounding EXACTLY;
//              g3 (~0.1%): wave-cooperative exact 512-scan (shfl-broadcast
//                x, 8 codes/lane, lexicographic reduce) - no extra kernel.
// Decision bound (V6-proven): screen error on score differences <= ~1e-4;
// DELTA = 2.5e-4 (2.5x margin). Exact path = round-0-proven fmaf/pairwise-8
// ordering -> argmin bitwise matches numpy.

#define KCODE 512
#define EMB   64
#define HWSZ  4096
#define NPOS  131072
#define DELTA 2.5e-4f

typedef short short8  __attribute__((ext_vector_type(8)));
typedef float float4v __attribute__((ext_vector_type(4)));

// ws float layout:
//   [0..1]        scratch flags: [1] = writer ticket
//   [8..1031]     writer block partials (1024)
//   [1032..1543]  e2 (numpy rounding, by code)
//   [1544..34311] bfrag short8[32][2][2][64] (128 KB)

// ---------- numpy-exact helpers ----------
__device__ __forceinline__ float np_sumsq64(const float* a) {
    #pragma clang fp contract(off)
    {
        float r0 = a[0] * a[0], r1 = a[1] * a[1], r2 = a[2] * a[2], r3 = a[3] * a[3];
        float r4 = a[4] * a[4], r5 = a[5] * a[5], r6 = a[6] * a[6], r7 = a[7] * a[7];
        for (int i = 8; i < 64; i += 8) {
            r0 += a[i + 0] * a[i + 0];
            r1 += a[i + 1] * a[i + 1];
            r2 += a[i + 2] * a[i + 2];
            r3 += a[i + 3] * a[i + 3];
            r4 += a[i + 4] * a[i + 4];
            r5 += a[i + 5] * a[i + 5];
            r6 += a[i + 6] * a[i + 6];
            r7 += a[i + 7] * a[i + 7];
        }
        return ((r0 + r1) + (r2 + r3)) + ((r4 + r5) + (r6 + r7));
    }
}

// split halves, identical accumulation order (a = dims 0..31, o = 32..63)
__device__ __forceinline__ float np_sumsq64_split(const float* a, const float* o) {
    #pragma clang fp contract(off)
    {
        float r0 = a[0] * a[0], r1 = a[1] * a[1], r2 = a[2] * a[2], r3 = a[3] * a[3];
        float r4 = a[4] * a[4], r5 = a[5] * a[5], r6 = a[6] * a[6], r7 = a[7] * a[7];
        for (int i = 8; i < 32; i += 8) {
            r0 += a[i + 0] * a[i + 0];  r1 += a[i + 1] * a[i + 1];
            r2 += a[i + 2] * a[i + 2];  r3 += a[i + 3] * a[i + 3];
            r4 += a[i + 4] * a[i + 4];  r5 += a[i + 5] * a[i + 5];
            r6 += a[i + 6] * a[i + 6];  r7 += a[i + 7] * a[i + 7];
        }
        for (int i = 0; i < 32; i += 8) {
            r0 += o[i + 0] * o[i + 0];  r1 += o[i + 1] * o[i + 1];
            r2 += o[i + 2] * o[i + 2];  r3 += o[i + 3] * o[i + 3];
            r4 += o[i + 4] * o[i + 4];  r5 += o[i + 5] * o[i + 5];
            r6 += o[i + 6] * o[i + 6];  r7 += o[i + 7] * o[i + 7];
        }
        return ((r0 + r1) + (r2 + r3)) + ((r4 + r5) + (r6 + r7));
    }
}

// exact numpy distance with split-half x: u = fl(fl(x2 - 2*xe) + e2k)
// (identical accumulation order to the round-0-proven exact_u)
__device__ __forceinline__ float exact_u_split2(const float* a, const float* o,
                                                float x2, const float* ek,
                                                float e2k) {
    float t0 = 0.f, t1 = 0.f, t2 = 0.f, t3 = 0.f;
    #pragma unroll
    for (int c = 0; c < 32; c += 4) {
        t0 = fmaf(a[c + 0], ek[c + 0], t0);
        t1 = fmaf(a[c + 1], ek[c + 1], t1);
        t2 = fmaf(a[c + 2], ek[c + 2], t2);
        t3 = fmaf(a[c + 3], ek[c + 3], t3);
    }
    #pragma unroll
    for (int c = 0; c < 32; c += 4) {
        t0 = fmaf(o[c + 0], ek[32 + c + 0], t0);
        t1 = fmaf(o[c + 1], ek[32 + c + 1], t1);
        t2 = fmaf(o[c + 2], ek[32 + c + 2], t2);
        t3 = fmaf(o[c + 3], ek[32 + c + 3], t3);
    }
    float xe  = (t0 + t1) + (t2 + t3);
    float tmp = x2 - 2.0f * xe;
    return tmp + e2k;
}

// shuffle-sourced variants for the wave-cooperative g3 scan: lane l holds x[l]
__device__ __forceinline__ float np_sumsq64_shfl(float xl) {
    #pragma clang fp contract(off)
    {
        float r[8];
        #pragma unroll
        for (int j = 0; j < 8; ++j) { float v = __shfl(xl, j, 64); r[j] = v * v; }
        #pragma unroll
        for (int i = 8; i < 64; i += 8)
            #pragma unroll
            for (int j = 0; j < 8; ++j) {
                float v = __shfl(xl, i + j, 64);
                r[j] += v * v;
            }
        return ((r[0] + r[1]) + (r[2] + r[3])) + ((r[4] + r[5]) + (r[6] + r[7]));
    }
}
__device__ __forceinline__ float exact_u_shfl(float xl, float x2,
                                              const float* ek, float e2k) {
    float t0 = 0.f, t1 = 0.f, t2 = 0.f, t3 = 0.f;
    #pragma unroll
    for (int c = 0; c < 64; c += 4) {
        t0 = fmaf(__shfl(xl, c + 0, 64), ek[c + 0], t0);
        t1 = fmaf(__shfl(xl, c + 1, 64), ek[c + 1], t1);
        t2 = fmaf(__shfl(xl, c + 2, 64), ek[c + 2], t2);
        t3 = fmaf(__shfl(xl, c + 3, 64), ek[c + 3], t3);
    }
    float xe  = (t0 + t1) + (t2 + t3);
    float tmp = x2 - 2.0f * xe;
    return tmp + e2k;
}

__device__ __forceinline__ unsigned short bf16rne(float f) {
    unsigned u = __float_as_uint(f);
    unsigned r = (u + 0x7FFFu + ((u >> 16) & 1u)) >> 16;
    return (unsigned short)r;
}
__device__ __forceinline__ float bf16tof(unsigned short h) {
    return __uint_as_float((unsigned)h << 16);
}

// sorted-insert of (v,i) into ((M1,I1),(M2,I2),M3); strict < keeps earlier.
#define INS(M1, I1, M2, I2, M3, v, i)                      \
    {                                                      \
        bool lt1 = (v) < (M1), lt2 = (v) < (M2), lt3 = (v) < (M3); \
        (M3) = lt2 ? (M2) : (lt3 ? (v) : (M3));            \
        (I2) = lt1 ? (I1) : (lt2 ? (i) : (I2));            \
        (M2) = lt1 ? (M1) : (lt2 ? (v) : (M2));            \
        (M1) = lt1 ? (v) : (M1);                           \
        (I1) = lt1 ? (i) : (I1);                           \
    }

// ---------- prep: e2 + bfrag + ticket zero ----------
__global__ void vq_prep(const float* __restrict__ emb, float* __restrict__ ws) {
    int f = blockIdx.x * blockDim.x + threadIdx.x;   // 0..4095
    if (f == 0) { ((unsigned*)ws)[0] = 0u; ((unsigned*)ws)[1] = 0u; }
    if (f < KCODE) ws[1032 + f] = np_sumsq64(emb + f * EMB);
    short8* bfrag = (short8*)(ws + 1544);
    int l = f & 63;
    int c = (f >> 6) & 1;
    int t = f >> 7;            // 0..31
    int code  = t * 16 + (l & 15);
    int dbase = 32 * c + ((l >> 4) & 3) * 8;
    const float* e = emb + code * EMB + dbase;
    short8 h, lo;
    #pragma unroll
    for (int j = 0; j < 8; ++j) {
        float v = e[j];
        unsigned short hb = bf16rne(v);
        float hf = bf16tof(hb);
        unsigned short lb = bf16rne(v - hf);
        h[j]  = (short)hb;
        lo[j] = (short)lb;
    }
    bfrag[t * 256 + c * 128 + 0 * 64 + l] = h;
    bfrag[t * 256 + c * 128 + 1 * 64 + l] = lo;
}

// ---------- screen: single MFMA sweep, top-3 tracking (V6-proven) ----------
__global__ __launch_bounds__(256, 3) void vq_screen(
        const float*  __restrict__ in,
        const float*  __restrict__ e2np,      // ws+1032
        const short8* __restrict__ bfrag,     // ws+1544
        float*        __restrict__ out_idx) { // packed {i1,i2,g2,g3}
    const int tid  = threadIdx.x;
    const int wave = tid >> 6;
    const int lane = tid & 63;
    const int lg   = lane >> 4;
    const int lc   = lane & 15;
    const int wavePos = blockIdx.x * 128 + wave * 32;

    // A-fragments: 2 pos-tiles x 2 dim-chunks, hi/lo of g = -2x.
    short8 fH[2][2], fL[2][2];
    #pragma unroll
    for (int pt = 0; pt < 2; ++pt) {
        int pos = wavePos + pt * 16 + lc;
        int b   = pos >> 12;
        int hw  = pos & (HWSZ - 1);
        const float* xb = in + ((size_t)b << 18) + hw;
        #pragma unroll
        for (int c = 0; c < 2; ++c) {
            short8 h, lo;
            #pragma unroll
            for (int j = 0; j < 8; ++j) {
                int d = 32 * c + lg * 8 + j;
                float g = -2.0f * xb[(size_t)d << 12];
                unsigned short hb = bf16rne(g);
                float hf = bf16tof(hb);
                unsigned short lb = bf16rne(g - hf);
                h[j]  = (short)hb;
                lo[j] = (short)lb;
            }
            fH[pt][c] = h;
            fL[pt][c] = lo;
        }
    }

    float m1[2][4], m2[2][4], m3[2][4];
    int   i1[2][4], i2[2][4];
    #pragma unroll
    for (int pt = 0; pt < 2; ++pt)
        #pragma unroll
        for (int r = 0; r < 4; ++r) {
            m1[pt][r] = 3.4e38f; m2[pt][r] = 3.4e38f; m3[pt][r] = 3.4e38f;
            i1[pt][r] = 0;       i2[pt][r] = 0;
        }

    short8 ceh0 = bfrag[lane],       cel0 = bfrag[64 + lane];
    short8 ceh1 = bfrag[128 + lane], cel1 = bfrag[192 + lane];
    float  ce2  = e2np[lc];
    #pragma unroll 2
    for (int t = 0; t < 32; ++t) {
        short8 neh0, nel0, neh1, nel1;
        float  ne2 = 0.0f;
        if (t < 31) {
            const short8* nb = bfrag + (t + 1) * 256;
            neh0 = nb[lane];       nel0 = nb[64 + lane];
            neh1 = nb[128 + lane]; nel1 = nb[192 + lane];
            ne2  = e2np[(t + 1) * 16 + lc];
        }
        const int kf = t * 16 + lc;
        #pragma unroll
        for (int pt = 0; pt < 2; ++pt) {
            float4v aH = {ce2, ce2, ce2, ce2};
            float4v aM = {0.f, 0.f, 0.f, 0.f};
            float4v aL = {0.f, 0.f, 0.f, 0.f};
            aH = __builtin_amdgcn_mfma_f32_16x16x32_bf16(fH[pt][0], ceh0, aH, 0, 0, 0);
            aM = __builtin_amdgcn_mfma_f32_16x16x32_bf16(fH[pt][0], cel0, aM, 0, 0, 0);
            aL = __builtin_amdgcn_mfma_f32_16x16x32_bf16(fL[pt][0], ceh0, aL, 0, 0, 0);
            aH = __builtin_amdgcn_mfma_f32_16x16x32_bf16(fH[pt][1], ceh1, aH, 0, 0, 0);
            aM = __builtin_amdgcn_mfma_f32_16x16x32_bf16(fH[pt][1], cel1, aM, 0, 0, 0);
            aL = __builtin_amdgcn_mfma_f32_16x16x32_bf16(fL[pt][1], ceh1, aL, 0, 0, 0);
            #pragma unroll
            for (int r = 0; r < 4; ++r) {
                float sv = (aH[r] + aM[r]) + aL[r];
                INS(m1[pt][r], i1[pt][r], m2[pt][r], i2[pt][r], m3[pt][r], sv, kf);
            }
        }
        ceh0 = neh0; cel0 = nel0; ceh1 = neh1; cel1 = nel1; ce2 = ne2;
    }

    #pragma unroll
    for (int pt = 0; pt < 2; ++pt) {
        #pragma unroll
        for (int r = 0; r < 4; ++r) {
            float M1 = m1[pt][r], M2 = m2[pt][r], M3 = m3[pt][r];
            int   I1 = i1[pt][r], I2 = i2[pt][r];
            #pragma unroll
            for (int d = 1; d <= 8; d <<= 1) {
                float pm1 = __shfl_xor(M1, d, 64);
                int   pi1 = __shfl_xor(I1, d, 64);
                float pm2 = __shfl_xor(M2, d, 64);
                int   pi2 = __shfl_xor(I2, d, 64);
                float pm3 = __shfl_xor(M3, d, 64);
                INS(M1, I1, M2, I2, M3, pm1, pi1);
                INS(M1, I1, M2, I2, M3, pm2, pi2);
                M3 = fminf(M3, pm3);
            }
            m1[pt][r] = M1; m2[pt][r] = M2; m3[pt][r] = M3;
            i1[pt][r] = I1; i2[pt][r] = I2;
        }
    }

    if (lc == 0) {
        #pragma unroll
        for (int pt = 0; pt < 2; ++pt) {
            #pragma unroll
            for (int r = 0; r < 4; ++r) {
                int p  = wavePos + pt * 16 + lg * 4 + r;
                int g2 = (m2[pt][r] - m1[pt][r] <= DELTA) ? 1 : 0;
                int g3 = (m3[pt][r] - m1[pt][r] <= DELTA) ? 1 : 0;
                int packed = i1[pt][r] | (i2[pt][r] << 9) | (g2 << 18) | (g3 << 19);
                out_idx[p] = (float)packed;
            }
        }
    }
}

// ---------- writer: 2 threads/position; resolve g2 solo, g3 cooperative ----
__global__ __launch_bounds__(256) void vq_write(
        const float* __restrict__ in, const float* __restrict__ emb,
        const float* __restrict__ e2np,
        float* __restrict__ out_idx, float* __restrict__ out_q,
        float* __restrict__ partials,           // ws+8, [1024]
        unsigned* __restrict__ ticket,          // ws+1
        float* __restrict__ out_loss) {
    const int tid  = threadIdx.x;
    const int wave = tid >> 6;
    const int lane = tid & 63;
    const int g    = blockIdx.x * 256 + tid;
    const int p    = g >> 1;                 // position
    const int h    = g & 1;                  // dim half
    const int b    = p >> 12;
    const int hw   = p & (HWSZ - 1);

    // this half's 32 x values (coalesced: pairs of lanes share hw range)
    const float* xp = in + ((size_t)b << 18) + ((size_t)(h * 32) << 12) + hw;
    float xh[32];
    #pragma unroll
    for (int c = 0; c < 32; ++c) xh[c] = xp[(size_t)c << 12];

    int v  = (int)out_idx[p];
    int kk = v & 511;
    const int fl = v >> 18;

    // g2-only resolve (~4% of positions): even lane, lane-local, exact order
    if (fl == 1 && h == 0) {
        float xo[32];
        const float* xp2 = in + ((size_t)b << 18) + ((size_t)32 << 12) + hw;
        #pragma unroll
        for (int c = 0; c < 32; ++c) xo[c] = xp2[(size_t)c << 12];
        float x2 = np_sumsq64_split(xh, xo);
        int ia = v & 511, ib = (v >> 9) & 511;
        float u1 = exact_u_split2(xh, xo, x2, emb + ia * EMB, e2np[ia]);
        float u2 = exact_u_split2(xh, xo, x2, emb + ib * EMB, e2np[ib]);
        kk = (u1 < u2) ? ia : (u2 < u1 ? ib : (ia < ib ? ia : ib));
    }

    // g3 resolve (~0.1%): wave-cooperative exact 512-scan per flagged position
    unsigned long long bm = __ballot((fl & 2) != 0 && h == 0);
    while (bm) {
        const int src = __ffsll((long long)bm) - 1;
        bm &= bm - 1;
        const int pn  = (blockIdx.x * 256 + wave * 64 + src) >> 1;
        const int bb  = pn >> 12;
        const int hww = pn & (HWSZ - 1);
        // lane l holds x[l]
        float xl = in[((size_t)bb << 18) + ((size_t)lane << 12) + hww];
        float x2 = np_sumsq64_shfl(xl);
        float bu = 3.4e38f;
        int   bk = 0x7fffffff;
        #pragma unroll
        for (int j = 0; j < 8; ++j) {
            int k = j * 64 + lane;
            float u = exact_u_shfl(xl, x2, emb + (size_t)k * EMB, e2np[k]);
            if (u < bu || (u == bu && k < bk)) { bu = u; bk = k; }
        }
        #pragma unroll
        for (int d = 1; d < 64; d <<= 1) {
            float ou = __shfl_xor(bu, d, 64);
            int   ok = __shfl_xor(bk, d, 64);
            if (ou < bu || (ou == bu && ok < bk)) { bu = ou; bk = ok; }
        }
        if ((lane >> 1) == (src >> 1)) kk = bk;   // both halves of the pair
    }

    // pair-broadcast resolved k (even lane authoritative) + index write
    kk = __shfl(kk, lane & ~1, 64);
    if (h == 0) out_idx[p] = (float)kk;

    // quantized output + loss partial over this half's 32 dims
    const float4* q4 = (const float4*)(emb + (size_t)kk * EMB + h * 32);
    float* op = out_q + ((size_t)b << 18) + ((size_t)(h * 32) << 12) + hw;
    float s = 0.0f;
    #pragma unroll
    for (int c4 = 0; c4 < 8; ++c4) {
        float4 q = q4[c4];
        float d0 = q.x - xh[c4 * 4 + 0];
        float d1 = q.y - xh[c4 * 4 + 1];
        float d2 = q.z - xh[c4 * 4 + 2];
        float d3 = q.w - xh[c4 * 4 + 3];
        s = fmaf(d0, d0, s); s = fmaf(d1, d1, s);
        s = fmaf(d2, d2, s); s = fmaf(d3, d3, s);
        op[(size_t)(c4 * 4 + 0) << 12] = q.x;
        op[(size_t)(c4 * 4 + 1) << 12] = q.y;
        op[(size_t)(c4 * 4 + 2) << 12] = q.z;
        op[(size_t)(c4 * 4 + 3) << 12] = q.w;
    }

    // deterministic-ish loss: wave shuffle -> LDS -> block partial -> ticket
    #pragma unroll
    for (int off = 32; off > 0; off >>= 1)
        s += __shfl_down(s, off, 64);
    __shared__ float red[4];
    if (lane == 0) red[wave] = s;
    __syncthreads();
    if (tid == 0) {
        partials[blockIdx.x] = (red[0] + red[1]) + (red[2] + red[3]);
        __threadfence();
        unsigned tk = atomicAdd(ticket, 1u);
        if (tk == 1023u) {
            __threadfence();
            float a0 = 0.f, a1 = 0.f, a2 = 0.f, a3 = 0.f;
            float a4 = 0.f, a5 = 0.f, a6 = 0.f, a7 = 0.f;
            for (int i = 0; i < 1024; i += 8) {
                a0 += partials[i + 0]; a1 += partials[i + 1];
                a2 += partials[i + 2]; a3 += partials[i + 3];
                a4 += partials[i + 4]; a5 += partials[i + 5];
                a6 += partials[i + 6]; a7 += partials[i + 7];
            }
            float tot = ((a0 + a1) + (a2 + a3)) + ((a4 + a5) + (a6 + a7));
            out_loss[0] = 1.25f * tot * (1.0f / ((float)NPOS * (float)EMB));
        }
    }
}

extern "C" void kernel_launch(void* const* d_in, const int* in_sizes, int n_in,
                              void* d_out, int out_size, void* d_ws, size_t ws_size,
                              hipStream_t stream) {
    const float* in  = (const float*)d_in[0];
    const float* emb = (const float*)d_in[1];
    float* ws  = (float*)d_ws;
    float* out = (float*)d_out;

    float*    out_loss = out;
    float*    out_q    = out + 1;
    float*    out_idx  = out + 1 + (size_t)NPOS * EMB;
    unsigned* ticket   = (unsigned*)ws + 1;
    float*    partials = ws + 8;                 // [1024]
    float*    e2np     = ws + 1032;              // [512]
    short8*   bfrag    = (short8*)(ws + 1544);   // 128 KB

    vq_prep<<<16, 256, 0, stream>>>(emb, ws);
    vq_screen<<<NPOS / 128, 256, 0, stream>>>(in, e2np, bfrag, out_idx);
    vq_write<<<NPOS * 2 / 256, 256, 0, stream>>>(in, emb, e2np, out_idx, out_q,
                                                 partials, ticket, out_loss);
}